// Round 3
// baseline (429.644 us; speedup 1.0000x reference)
//
#include <hip/hip_runtime.h>

// Problem constants
constexpr int CXR = 15, ECG = 14, EHR = 13;
constexpr int TOTAL = 42;          // CXR+ECG+EHR
constexpr int MPITCH = 44;         // padded row pitch (16B-aligned rows)
constexpr float LN_EPS = 1e-5f;

// Workspace layout (floats)
constexpr int WS_M    = 0;                   // fused matrix, 42 rows x 44 pitch
constexpr int WS_B    = TOTAL * MPITCH;      // 1848: fused bias (42)
constexpr int WS_G    = WS_B + TOTAL;        // ln gamma (42)
constexpr int WS_BETA = WS_G + TOTAL;        // ln beta  (42)
constexpr int WS_FLOATS = WS_BETA + TOTAL;

// Main-kernel tiling: 256 rows/block, one LDS buffer sized for widest segment
constexpr int ROWS = 256;
constexpr int SBUF_FLOATS = ROWS * CXR;      // 3840 floats = 15 KB -> 8 blocks/CU

// ---- constant-address-space weight access (forces s_load scalar path) ----
typedef float f4v __attribute__((ext_vector_type(4)));
typedef __attribute__((address_space(4))) const f4v   CF4;
typedef __attribute__((address_space(4))) const float CFc;

__device__ __forceinline__ CF4* cast4(const float* p) {
    return (CF4*)(unsigned long long)p;
}
__device__ __forceinline__ CFc* cast1(const float* p) {
    return (CFc*)(unsigned long long)p;
}

struct FuseArgs {
    const float *in_w, *in_b, *out_w, *out_b, *kv_w, *kv_b, *ln_g, *ln_b;
    int E, R;
};

// One block per branch: A_eff = out_w @ Wv @ kv_w (E x 42),
// b_eff = out_w @ (Wv @ kv_b + bv) + out_b, plus ln gamma/beta copy.
__global__ void fuse_weights_kernel(FuseArgs a0, FuseArgs a1, FuseArgs a2,
                                    float* __restrict__ ws) {
    FuseArgs a = (blockIdx.x == 0) ? a0 : (blockIdx.x == 1 ? a1 : a2);
    const int E = a.E, R = a.R;
    const int tid = threadIdx.x;

    __shared__ float T1[15 * 42];
    __shared__ float b1[15];

    for (int idx = tid; idx < E * TOTAL; idx += blockDim.x) {
        int i = idx / TOTAL, j = idx % TOTAL;
        float acc = 0.f;
        for (int k = 0; k < E; ++k)
            acc = fmaf(a.in_w[(2 * E + i) * E + k], a.kv_w[k * TOTAL + j], acc);
        T1[i * TOTAL + j] = acc;
    }
    if (tid < E) {
        float acc = a.in_b[2 * E + tid];
        for (int k = 0; k < E; ++k)
            acc = fmaf(a.in_w[(2 * E + tid) * E + k], a.kv_b[k], acc);
        b1[tid] = acc;
    }
    __syncthreads();

    for (int idx = tid; idx < E * MPITCH; idx += blockDim.x) {
        int i = idx / MPITCH, j = idx % MPITCH;
        float acc = 0.f;
        if (j < TOTAL)
            for (int k = 0; k < E; ++k)
                acc = fmaf(a.out_w[i * E + k], T1[k * TOTAL + j], acc);
        ws[WS_M + (R + i) * MPITCH + j] = acc;
    }
    if (tid < E) {
        float acc = a.out_b[tid];
        for (int k = 0; k < E; ++k)
            acc = fmaf(a.out_w[tid * E + k], b1[k], acc);
        ws[WS_B + R + tid]    = acc;
        ws[WS_G + R + tid]    = a.ln_g[tid];
        ws[WS_BETA + R + tid] = a.ln_b[tid];
    }
}

// Compute one segment's outputs (y + LN), stage into LDS, coalesced store.
template <int E, int R, bool LAST>
__device__ __forceinline__ void process_seg(const float (&ctx)[MPITCH],
                                            const float* __restrict__ ws,
                                            float* __restrict__ sbuf,
                                            float4* __restrict__ st4,
                                            int tid,
                                            float4* __restrict__ out4) {
    float y[E];
#pragma unroll
    for (int i = 0; i < E; ++i) {
        CF4* wrow = cast4(ws + WS_M + (R + i) * MPITCH);
        float acc = *cast1(ws + WS_B + R + i);
#pragma unroll
        for (int q = 0; q < MPITCH / 4; ++q) {
            f4v w = wrow[q];                    // s_load_dwordx4 (scalar pipe)
            acc = fmaf(w.x, ctx[4 * q + 0], acc);
            acc = fmaf(w.y, ctx[4 * q + 1], acc);
            acc = fmaf(w.z, ctx[4 * q + 2], acc);
            acc = fmaf(w.w, ctx[4 * q + 3], acc);
        }
        y[i] = ctx[R + i] + acc;                // residual
    }
    float mu = 0.f;
#pragma unroll
    for (int i = 0; i < E; ++i) mu += y[i];
    mu *= (1.0f / E);
    float var = 0.f;
#pragma unroll
    for (int i = 0; i < E; ++i) { float d = y[i] - mu; var = fmaf(d, d, var); }
    var *= (1.0f / E);
    float rs = rsqrtf(var + LN_EPS);
#pragma unroll
    for (int i = 0; i < E; ++i) {
        float n = (y[i] - mu) * rs;
        sbuf[tid * E + i] = fmaf(n, *cast1(ws + WS_G + R + i),
                                 *cast1(ws + WS_BETA + R + i));
    }
    __syncthreads();
    constexpr int N = ROWS * E / 4;
#pragma unroll
    for (int it = 0; it < 4; ++it) {
        int idx = tid + it * 256;
        if (idx < N) out4[idx] = st4[idx];
    }
    if (!LAST) __syncthreads();
}

__global__ __launch_bounds__(256, 4) void cmca_main(
        const float* __restrict__ cxr, const float* __restrict__ ecg,
        const float* __restrict__ ehr, const float* __restrict__ ws,
        float* __restrict__ out_cxr, float* __restrict__ out_ecg,
        float* __restrict__ out_ehr) {
    __shared__ __align__(16) float sbuf[SBUF_FLOATS];
    float4* st4 = (float4*)sbuf;
    const int tid = threadIdx.x;
    const size_t tile = blockIdx.x;

    constexpr int N0 = ROWS * CXR / 4;   // 960
    constexpr int N1 = ROWS * ECG / 4;   // 896
    constexpr int N2 = ROWS * EHR / 4;   // 832
    const float4* g0 = (const float4*)(cxr + tile * (size_t)(ROWS * CXR));
    const float4* g1 = (const float4*)(ecg + tile * (size_t)(ROWS * ECG));
    const float4* g2 = (const float4*)(ehr + tile * (size_t)(ROWS * EHR));

    // ---- issue ALL global loads up front (latency paid once, overlapped) ----
    float4 r0[4], r1[4], r2[4];
#pragma unroll
    for (int it = 0; it < 4; ++it) { int idx = tid + it * 256; if (idx < N0) r0[it] = g0[idx]; }
#pragma unroll
    for (int it = 0; it < 4; ++it) { int idx = tid + it * 256; if (idx < N1) r1[it] = g1[idx]; }
#pragma unroll
    for (int it = 0; it < 4; ++it) { int idx = tid + it * 256; if (idx < N2) r2[it] = g2[idx]; }

    // ---- transpose each segment through the shared 15 KB buffer ----
    float ctx[MPITCH];
#pragma unroll
    for (int it = 0; it < 4; ++it) { int idx = tid + it * 256; if (idx < N0) st4[idx] = r0[it]; }
    __syncthreads();
#pragma unroll
    for (int j = 0; j < CXR; ++j) ctx[j] = sbuf[tid * CXR + j];
    __syncthreads();

#pragma unroll
    for (int it = 0; it < 4; ++it) { int idx = tid + it * 256; if (idx < N1) st4[idx] = r1[it]; }
    __syncthreads();
#pragma unroll
    for (int j = 0; j < ECG; ++j) ctx[CXR + j] = sbuf[tid * ECG + j];
    __syncthreads();

#pragma unroll
    for (int it = 0; it < 4; ++it) { int idx = tid + it * 256; if (idx < N2) st4[idx] = r2[it]; }
    __syncthreads();
#pragma unroll
    for (int j = 0; j < EHR; ++j) ctx[CXR + ECG + j] = sbuf[tid * EHR + j];
    __syncthreads();

    ctx[42] = 0.f;
    ctx[43] = 0.f;

    // ---- per-segment matvec (weights via scalar loads) + LN + store ----
    process_seg<CXR, 0, false>(ctx, ws, sbuf, st4, tid,
                               (float4*)(out_cxr + tile * (size_t)(ROWS * CXR)));
    process_seg<ECG, CXR, false>(ctx, ws, sbuf, st4, tid,
                               (float4*)(out_ecg + tile * (size_t)(ROWS * ECG)));
    process_seg<EHR, CXR + ECG, true>(ctx, ws, sbuf, st4, tid,
                               (float4*)(out_ehr + tile * (size_t)(ROWS * EHR)));
}

extern "C" void kernel_launch(void* const* d_in, const int* in_sizes, int n_in,
                              void* d_out, int out_size, void* d_ws, size_t ws_size,
                              hipStream_t stream) {
    const float* cxr = (const float*)d_in[0];
    const float* ecg = (const float*)d_in[1];
    const float* ehr = (const float*)d_in[2];
    float* ws = (float*)d_ws;
    float* out = (float*)d_out;

    const size_t Bn = (size_t)in_sizes[0] / CXR;   // 2097152

    auto mk = [&](int base, int E, int R) {
        FuseArgs a;
        a.in_w  = (const float*)d_in[base + 0];
        a.in_b  = (const float*)d_in[base + 1];
        a.out_w = (const float*)d_in[base + 2];
        a.out_b = (const float*)d_in[base + 3];
        a.kv_w  = (const float*)d_in[base + 4];
        a.kv_b  = (const float*)d_in[base + 5];
        a.ln_g  = (const float*)d_in[base + 6];
        a.ln_b  = (const float*)d_in[base + 7];
        a.E = E; a.R = R;
        return a;
    };
    FuseArgs a0 = mk(3, CXR, 0);
    FuseArgs a1 = mk(11, ECG, CXR);
    FuseArgs a2 = mk(19, EHR, CXR + ECG);

    fuse_weights_kernel<<<3, 256, 0, stream>>>(a0, a1, a2, ws);

    const int tiles = (int)(Bn / ROWS);   // 8192
    cmca_main<<<tiles, 256, 0, stream>>>(cxr, ecg, ehr, ws,
                                         out,
                                         out + Bn * CXR,
                                         out + Bn * (CXR + ECG));
}

// Round 4
// 225.266 us; speedup vs baseline: 1.9073x; 1.9073x over previous
//
#include <hip/hip_runtime.h>

// Problem constants
constexpr int CXR = 15, ECG = 14, EHR = 13;
constexpr int TOTAL = 42;          // CXR+ECG+EHR
constexpr int MPITCH = 44;         // padded row pitch (16B-aligned rows)
constexpr float LN_EPS = 1e-5f;

// Workspace layout (floats)
constexpr int WS_M    = 0;                   // fused matrix, 42 rows x 44 pitch
constexpr int WS_B    = TOTAL * MPITCH;      // fused bias (42)
constexpr int WS_G    = WS_B + TOTAL;        // ln gamma (42)
constexpr int WS_BETA = WS_G + TOTAL;        // ln beta  (42)
constexpr int WS_FLOATS = WS_BETA + TOTAL;

// Main-kernel tiling: 256 rows/block, one LDS buffer sized for widest segment
constexpr int ROWS = 256;
constexpr int SBUF_FLOATS = ROWS * CXR;      // 3840 floats = 15 KB

// ---- constant-address-space weight access (scalar s_load path) ----
typedef float f4v __attribute__((ext_vector_type(4)));
typedef __attribute__((address_space(4))) const f4v   CF4;
typedef __attribute__((address_space(4))) const float CFc;

__device__ __forceinline__ CF4* cast4(const float* p) {
    return (CF4*)(unsigned long long)p;
}
__device__ __forceinline__ CFc* cast1(const float* p) {
    return (CFc*)(unsigned long long)p;
}

struct FuseArgs {
    const float *in_w, *in_b, *out_w, *out_b, *kv_w, *kv_b, *ln_g, *ln_b;
    int E, R;
};

// One block per branch: A_eff = out_w @ Wv @ kv_w (E x 42),
// b_eff = out_w @ (Wv @ kv_b + bv) + out_b, plus ln gamma/beta copy.
__global__ void fuse_weights_kernel(FuseArgs a0, FuseArgs a1, FuseArgs a2,
                                    float* __restrict__ ws) {
    FuseArgs a = (blockIdx.x == 0) ? a0 : (blockIdx.x == 1 ? a1 : a2);
    const int E = a.E, R = a.R;
    const int tid = threadIdx.x;

    __shared__ float T1[15 * 42];
    __shared__ float b1[15];

    for (int idx = tid; idx < E * TOTAL; idx += blockDim.x) {
        int i = idx / TOTAL, j = idx % TOTAL;
        float acc = 0.f;
        for (int k = 0; k < E; ++k)
            acc = fmaf(a.in_w[(2 * E + i) * E + k], a.kv_w[k * TOTAL + j], acc);
        T1[i * TOTAL + j] = acc;
    }
    if (tid < E) {
        float acc = a.in_b[2 * E + tid];
        for (int k = 0; k < E; ++k)
            acc = fmaf(a.in_w[(2 * E + tid) * E + k], a.kv_b[k], acc);
        b1[tid] = acc;
    }
    __syncthreads();

    for (int idx = tid; idx < E * MPITCH; idx += blockDim.x) {
        int i = idx / MPITCH, j = idx % MPITCH;
        float acc = 0.f;
        if (j < TOTAL)
            for (int k = 0; k < E; ++k)
                acc = fmaf(a.out_w[i * E + k], T1[k * TOTAL + j], acc);
        ws[WS_M + (R + i) * MPITCH + j] = acc;
    }
    if (tid < E) {
        float acc = a.out_b[tid];
        for (int k = 0; k < E; ++k)
            acc = fmaf(a.out_w[tid * E + k], b1[k], acc);
        ws[WS_B + R + tid]    = acc;
        ws[WS_G + R + tid]    = a.ln_g[tid];
        ws[WS_BETA + R + tid] = a.ln_b[tid];
    }
}

// Compute one segment (matvec from scalar-loaded weights + residual + LN),
// stage into LDS, coalesced float4 store.
template <int E, int R, bool LAST>
__device__ __forceinline__ void process_seg(const float (&ctx)[MPITCH],
                                            const float* __restrict__ ws,
                                            float* __restrict__ sbuf,
                                            float4* __restrict__ st4,
                                            int tid,
                                            float4* __restrict__ out4) {
    float y[E];
#pragma unroll
    for (int i = 0; i < E; ++i) {
        CF4* wrow = cast4(ws + WS_M + (R + i) * MPITCH);
        float acc = *cast1(ws + WS_B + R + i);
#pragma unroll
        for (int q = 0; q < MPITCH / 4; ++q) {
            f4v w = wrow[q];                    // s_load_dwordx4 (scalar pipe)
            acc = fmaf(w.x, ctx[4 * q + 0], acc);
            acc = fmaf(w.y, ctx[4 * q + 1], acc);
            acc = fmaf(w.z, ctx[4 * q + 2], acc);
            acc = fmaf(w.w, ctx[4 * q + 3], acc);
        }
        y[i] = ctx[R + i] + acc;                // residual
    }
    float mu = 0.f;
#pragma unroll
    for (int i = 0; i < E; ++i) mu += y[i];
    mu *= (1.0f / E);
    float var = 0.f;
#pragma unroll
    for (int i = 0; i < E; ++i) { float d = y[i] - mu; var = fmaf(d, d, var); }
    var *= (1.0f / E);
    float rs = rsqrtf(var + LN_EPS);
#pragma unroll
    for (int i = 0; i < E; ++i) {
        float n = (y[i] - mu) * rs;
        sbuf[tid * E + i] = fmaf(n, *cast1(ws + WS_G + R + i),
                                 *cast1(ws + WS_BETA + R + i));
    }
    __syncthreads();
    constexpr int N = ROWS * E / 4;
#pragma unroll
    for (int it = 0; it < 4; ++it) {
        int idx = tid + it * 256;
        if (idx < N) out4[idx] = st4[idx];
    }
    if (!LAST) __syncthreads();
}

__global__ __launch_bounds__(256) void cmca_main(
        const float* __restrict__ cxr, const float* __restrict__ ecg,
        const float* __restrict__ ehr, const float* __restrict__ ws,
        float* __restrict__ out_cxr, float* __restrict__ out_ecg,
        float* __restrict__ out_ehr) {
    __shared__ __align__(16) float sbuf[SBUF_FLOATS];
    float4* st4 = (float4*)sbuf;
    const int tid = threadIdx.x;
    const size_t tile = blockIdx.x;

    constexpr int N0 = ROWS * CXR / 4;   // 960
    constexpr int N1 = ROWS * ECG / 4;   // 896
    constexpr int N2 = ROWS * EHR / 4;   // 832
    const float4* g0 = (const float4*)(cxr + tile * (size_t)(ROWS * CXR));
    const float4* g1 = (const float4*)(ecg + tile * (size_t)(ROWS * ECG));
    const float4* g2 = (const float4*)(ehr + tile * (size_t)(ROWS * EHR));

    float ctx[MPITCH];

    // ---- seg0: global -> LDS -> registers ----
#pragma unroll
    for (int it = 0; it < 4; ++it) { int idx = tid + it * 256; if (idx < N0) st4[idx] = g0[idx]; }
    __syncthreads();
#pragma unroll
    for (int j = 0; j < CXR; ++j) ctx[j] = sbuf[tid * CXR + j];
    __syncthreads();

    // ---- seg1 ----
#pragma unroll
    for (int it = 0; it < 4; ++it) { int idx = tid + it * 256; if (idx < N1) st4[idx] = g1[idx]; }
    __syncthreads();
#pragma unroll
    for (int j = 0; j < ECG; ++j) ctx[CXR + j] = sbuf[tid * ECG + j];
    __syncthreads();

    // ---- seg2 ----
#pragma unroll
    for (int it = 0; it < 4; ++it) { int idx = tid + it * 256; if (idx < N2) st4[idx] = g2[idx]; }
    __syncthreads();
#pragma unroll
    for (int j = 0; j < EHR; ++j) ctx[CXR + ECG + j] = sbuf[tid * EHR + j];
    __syncthreads();

    ctx[42] = 0.f;
    ctx[43] = 0.f;

    // ---- per-segment matvec (weights via scalar loads) + LN + store ----
    process_seg<CXR, 0, false>(ctx, ws, sbuf, st4, tid,
                               (float4*)(out_cxr + tile * (size_t)(ROWS * CXR)));
    process_seg<ECG, CXR, false>(ctx, ws, sbuf, st4, tid,
                               (float4*)(out_ecg + tile * (size_t)(ROWS * ECG)));
    process_seg<EHR, CXR + ECG, true>(ctx, ws, sbuf, st4, tid,
                               (float4*)(out_ehr + tile * (size_t)(ROWS * EHR)));
}

extern "C" void kernel_launch(void* const* d_in, const int* in_sizes, int n_in,
                              void* d_out, int out_size, void* d_ws, size_t ws_size,
                              hipStream_t stream) {
    const float* cxr = (const float*)d_in[0];
    const float* ecg = (const float*)d_in[1];
    const float* ehr = (const float*)d_in[2];
    float* ws = (float*)d_ws;
    float* out = (float*)d_out;

    const size_t Bn = (size_t)in_sizes[0] / CXR;   // 2097152

    auto mk = [&](int base, int E, int R) {
        FuseArgs a;
        a.in_w  = (const float*)d_in[base + 0];
        a.in_b  = (const float*)d_in[base + 1];
        a.out_w = (const float*)d_in[base + 2];
        a.out_b = (const float*)d_in[base + 3];
        a.kv_w  = (const float*)d_in[base + 4];
        a.kv_b  = (const float*)d_in[base + 5];
        a.ln_g  = (const float*)d_in[base + 6];
        a.ln_b  = (const float*)d_in[base + 7];
        a.E = E; a.R = R;
        return a;
    };
    FuseArgs a0 = mk(3, CXR, 0);
    FuseArgs a1 = mk(11, ECG, CXR);
    FuseArgs a2 = mk(19, EHR, CXR + ECG);

    fuse_weights_kernel<<<3, 256, 0, stream>>>(a0, a1, a2, ws);

    const int tiles = (int)(Bn / ROWS);   // 8192
    cmca_main<<<tiles, 256, 0, stream>>>(cxr, ecg, ehr, ws,
                                         out,
                                         out + Bn * CXR,
                                         out + Bn * (CXR + ECG));
}

// Round 5
// 176.657 us; speedup vs baseline: 2.4321x; 1.2752x over previous
//
#include <hip/hip_runtime.h>
#include <stdint.h>

// Problem constants
constexpr int CXR = 15, ECG = 14, EHR = 13;
constexpr int TOTAL = 42;          // CXR+ECG+EHR
constexpr int MPITCH = 44;         // padded fused-matrix row pitch
constexpr float LN_EPS = 1e-5f;

// Workspace layout (floats)
constexpr int WS_M    = 0;                   // fused matrix, 42 rows x 44 pitch
constexpr int WS_B    = TOTAL * MPITCH;      // fused bias (42)
constexpr int WS_G    = WS_B + TOTAL;        // ln gamma (42)
constexpr int WS_BETA = WS_G + TOTAL;        // ln beta  (42)
constexpr int WS_FLOATS = WS_BETA + TOTAL;

// Main-kernel tiling: 256 rows/block, ALL three segments resident in LDS
constexpr int ROWS = 256;
constexpr int S0 = 0;                        // float offsets of the 3 segments
constexpr int S1 = ROWS * CXR;               // 3840
constexpr int S2 = S1 + ROWS * ECG;          // 7424
constexpr int STAGE_FLOATS = S2 + ROWS * EHR;// 10752 floats = 43008 B
constexpr int C0 = ROWS * CXR / 4;           // 960  16B chunks (mult of 64)
constexpr int C1 = ROWS * ECG / 4;           // 896
constexpr int C2 = ROWS * EHR / 4;           // 832

// ---- constant-address-space weight access (scalar s_load path) ----
typedef float f4v __attribute__((ext_vector_type(4)));
typedef __attribute__((address_space(4))) const f4v   CF4;
typedef __attribute__((address_space(4))) const float CFc;

__device__ __forceinline__ CF4* cast4(const float* p) {
    return (CF4*)(unsigned long long)p;
}
__device__ __forceinline__ CFc* cast1(const float* p) {
    return (CFc*)(unsigned long long)p;
}

struct FuseArgs {
    const float *in_w, *in_b, *out_w, *out_b, *kv_w, *kv_b, *ln_g, *ln_b;
    int E, R;
};

// One block per branch: A_eff = out_w @ Wv @ kv_w (E x 42),
// b_eff = out_w @ (Wv @ kv_b + bv) + out_b, plus ln gamma/beta copy.
__global__ void fuse_weights_kernel(FuseArgs a0, FuseArgs a1, FuseArgs a2,
                                    float* __restrict__ ws) {
    FuseArgs a = (blockIdx.x == 0) ? a0 : (blockIdx.x == 1 ? a1 : a2);
    const int E = a.E, R = a.R;
    const int tid = threadIdx.x;

    __shared__ float T1[15 * 42];
    __shared__ float b1[15];

    for (int idx = tid; idx < E * TOTAL; idx += blockDim.x) {
        int i = idx / TOTAL, j = idx % TOTAL;
        float acc = 0.f;
        for (int k = 0; k < E; ++k)
            acc = fmaf(a.in_w[(2 * E + i) * E + k], a.kv_w[k * TOTAL + j], acc);
        T1[i * TOTAL + j] = acc;
    }
    if (tid < E) {
        float acc = a.in_b[2 * E + tid];
        for (int k = 0; k < E; ++k)
            acc = fmaf(a.in_w[(2 * E + tid) * E + k], a.kv_b[k], acc);
        b1[tid] = acc;
    }
    __syncthreads();

    for (int idx = tid; idx < E * MPITCH; idx += blockDim.x) {
        int i = idx / MPITCH, j = idx % MPITCH;
        float acc = 0.f;
        if (j < TOTAL)
            for (int k = 0; k < E; ++k)
                acc = fmaf(a.out_w[i * E + k], T1[k * TOTAL + j], acc);
        ws[WS_M + (R + i) * MPITCH + j] = acc;
    }
    if (tid < E) {
        float acc = a.out_b[tid];
        for (int k = 0; k < E; ++k)
            acc = fmaf(a.out_w[tid * E + k], b1[k], acc);
        ws[WS_B + R + tid]    = acc;
        ws[WS_G + R + tid]    = a.ln_g[tid];
        ws[WS_BETA + R + tid] = a.ln_b[tid];
    }
}

// Async global->LDS staging, width 16, linear layout. LDS dest must be the
// wave-uniform base (HW adds lane*16); global src is per-lane.
__device__ __forceinline__ void stage_seg(const float* __restrict__ g,
                                          float* sbase, int nchunks, int tid) {
    const int wbase = tid & ~63;             // lane0's chunk slot this iteration
#pragma unroll
    for (int it = 0; it < 4; ++it) {
        int idx = tid + it * 256;
        if (idx < nchunks) {                  // wave-uniform (nchunks % 64 == 0)
            const __attribute__((address_space(1))) void* src =
                (const __attribute__((address_space(1))) void*)
                    ((const char*)g + (size_t)idx * 16);
            __attribute__((address_space(3))) void* dst =
                (__attribute__((address_space(3))) void*)
                    ((char*)sbase + (size_t)(wbase + it * 256) * 16);
            __builtin_amdgcn_global_load_lds(src, dst, 16, 0, 0);
        }
    }
}

// Matvec (scalar-loaded fused weights) + residual + LN; result -> LDS.
template <int E, int R, int SBASE>
__device__ __forceinline__ void compute_seg(const float (&ctx)[MPITCH],
                                            const float* __restrict__ ws,
                                            float* __restrict__ sbuf, int tid) {
    float y[E];
#pragma unroll
    for (int i = 0; i < E; ++i) {
        CF4* wrow = cast4(ws + WS_M + (R + i) * MPITCH);
        float acc = *cast1(ws + WS_B + R + i);
#pragma unroll
        for (int q = 0; q < MPITCH / 4; ++q) {
            f4v w = wrow[q];                  // s_load_dwordx4 (scalar pipe)
            acc = fmaf(w.x, ctx[4 * q + 0], acc);
            acc = fmaf(w.y, ctx[4 * q + 1], acc);
            acc = fmaf(w.z, ctx[4 * q + 2], acc);
            acc = fmaf(w.w, ctx[4 * q + 3], acc);
        }
        y[i] = ctx[R + i] + acc;              // residual
    }
    float mu = 0.f;
#pragma unroll
    for (int i = 0; i < E; ++i) mu += y[i];
    mu *= (1.0f / E);
    float var = 0.f;
#pragma unroll
    for (int i = 0; i < E; ++i) { float d = y[i] - mu; var = fmaf(d, d, var); }
    var *= (1.0f / E);
    float rs = rsqrtf(var + LN_EPS);
#pragma unroll
    for (int i = 0; i < E; ++i) {
        float n = (y[i] - mu) * rs;
        sbuf[SBASE + tid * E + i] = fmaf(n, *cast1(ws + WS_G + R + i),
                                         *cast1(ws + WS_BETA + R + i));
    }
}

__global__ __launch_bounds__(256) void cmca_main(
        const float* __restrict__ cxr, const float* __restrict__ ecg,
        const float* __restrict__ ehr, const float* __restrict__ ws,
        float* __restrict__ out_cxr, float* __restrict__ out_ecg,
        float* __restrict__ out_ehr) {
    __shared__ __align__(16) float sbuf[STAGE_FLOATS];
    float4* st4 = (float4*)sbuf;
    const int tid = threadIdx.x;
    const size_t tile = blockIdx.x;

    const float* g0 = cxr + tile * (size_t)(ROWS * CXR);
    const float* g1 = ecg + tile * (size_t)(ROWS * ECG);
    const float* g2 = ehr + tile * (size_t)(ROWS * EHR);

    // ---- single staging phase: all three segments, async to LDS ----
    stage_seg(g0, sbuf + S0, C0, tid);
    stage_seg(g1, sbuf + S1, C1, tid);
    stage_seg(g2, sbuf + S2, C2, tid);
    __syncthreads();                          // drains vmcnt, one exposure

    // ---- gather this thread's row ----
    float ctx[MPITCH];
#pragma unroll
    for (int j = 0; j < CXR; ++j) ctx[j] = sbuf[S0 + tid * CXR + j];
#pragma unroll
    for (int j = 0; j < ECG; ++j) ctx[CXR + j] = sbuf[S1 + tid * ECG + j];
#pragma unroll
    for (int j = 0; j < EHR; ++j) ctx[CXR + ECG + j] = sbuf[S2 + tid * EHR + j];
    __syncthreads();                          // protect buffer overwrite
    ctx[42] = 0.f;
    ctx[43] = 0.f;

    // ---- all three segments, register-only, results back into LDS ----
    compute_seg<CXR, 0, S0>(ctx, ws, sbuf, tid);
    compute_seg<ECG, CXR, S1>(ctx, ws, sbuf, tid);
    compute_seg<EHR, CXR + ECG, S2>(ctx, ws, sbuf, tid);
    __syncthreads();

    // ---- coalesced float4 stores, all three segments ----
    float4* o0 = (float4*)(out_cxr + tile * (size_t)(ROWS * CXR));
    float4* o1 = (float4*)(out_ecg + tile * (size_t)(ROWS * ECG));
    float4* o2 = (float4*)(out_ehr + tile * (size_t)(ROWS * EHR));
#pragma unroll
    for (int it = 0; it < 4; ++it) {
        int idx = tid + it * 256;
        if (idx < C0) o0[idx] = st4[idx];
    }
#pragma unroll
    for (int it = 0; it < 4; ++it) {
        int idx = tid + it * 256;
        if (idx < C1) o1[idx] = st4[C0 + idx];
    }
#pragma unroll
    for (int it = 0; it < 4; ++it) {
        int idx = tid + it * 256;
        if (idx < C2) o2[idx] = st4[C0 + C1 + idx];
    }
}

extern "C" void kernel_launch(void* const* d_in, const int* in_sizes, int n_in,
                              void* d_out, int out_size, void* d_ws, size_t ws_size,
                              hipStream_t stream) {
    const float* cxr = (const float*)d_in[0];
    const float* ecg = (const float*)d_in[1];
    const float* ehr = (const float*)d_in[2];
    float* ws = (float*)d_ws;
    float* out = (float*)d_out;

    const size_t Bn = (size_t)in_sizes[0] / CXR;   // 2097152

    auto mk = [&](int base, int E, int R) {
        FuseArgs a;
        a.in_w  = (const float*)d_in[base + 0];
        a.in_b  = (const float*)d_in[base + 1];
        a.out_w = (const float*)d_in[base + 2];
        a.out_b = (const float*)d_in[base + 3];
        a.kv_w  = (const float*)d_in[base + 4];
        a.kv_b  = (const float*)d_in[base + 5];
        a.ln_g  = (const float*)d_in[base + 6];
        a.ln_b  = (const float*)d_in[base + 7];
        a.E = E; a.R = R;
        return a;
    };
    FuseArgs a0 = mk(3, CXR, 0);
    FuseArgs a1 = mk(11, ECG, CXR);
    FuseArgs a2 = mk(19, EHR, CXR + ECG);

    fuse_weights_kernel<<<3, 256, 0, stream>>>(a0, a1, a2, ws);

    const int tiles = (int)(Bn / ROWS);   // 8192
    cmca_main<<<tiles, 256, 0, stream>>>(cxr, ecg, ehr, ws,
                                         out,
                                         out + Bn * CXR,
                                         out + Bn * (CXR + ECG));
}

// Round 6
// 172.252 us; speedup vs baseline: 2.4943x; 1.0256x over previous
//
#include <hip/hip_runtime.h>
#include <stdint.h>

// Problem constants
constexpr int CXR = 15, ECG = 14, EHR = 13;
constexpr int TOTAL = 42;          // CXR+ECG+EHR
constexpr int MPITCH = 44;         // padded fused-matrix row pitch
constexpr float LN_EPS = 1e-5f;

// Workspace layout (floats)
constexpr int WS_M    = 0;                   // fused matrix, 42 rows x 44 pitch
constexpr int WS_B    = TOTAL * MPITCH;      // fused bias (42)
constexpr int WS_G    = WS_B + TOTAL;        // ln gamma (42)
constexpr int WS_BETA = WS_G + TOTAL;        // ln beta  (42)
constexpr int WS_FLOATS = WS_BETA + TOTAL;

// Wave-autonomous tiling: 64 rows per wave, 2 waves per block
constexpr int WROWS = 64;
constexpr int WFLOATS = WROWS * TOTAL;       // 2688 floats = 10752 B per wave
constexpr int WS0F = 0;                      // float offsets inside wave slice
constexpr int WS1F = WROWS * CXR;            // 960
constexpr int WS2F = WS1F + WROWS * ECG;     // 1856
constexpr int WC0 = WROWS * CXR / 4;         // 240 16B chunks
constexpr int WC1 = WROWS * ECG / 4;         // 224
constexpr int WC2 = WROWS * EHR / 4;         // 208

// ---- constant-address-space weight access (scalar s_load path) ----
typedef float f2v __attribute__((ext_vector_type(2)));
typedef __attribute__((address_space(4))) const f2v   CF2;
typedef __attribute__((address_space(4))) const float CFc;

__device__ __forceinline__ CF2* cast2(const float* p) {
    return (CF2*)(unsigned long long)p;
}
__device__ __forceinline__ CFc* cast1(const float* p) {
    return (CFc*)(unsigned long long)p;
}

struct FuseArgs {
    const float *in_w, *in_b, *out_w, *out_b, *kv_w, *kv_b, *ln_g, *ln_b;
    int E, R;
};

// One block per branch: A_eff = out_w @ Wv @ kv_w (E x 42),
// b_eff = out_w @ (Wv @ kv_b + bv) + out_b, plus ln gamma/beta copy.
__global__ void fuse_weights_kernel(FuseArgs a0, FuseArgs a1, FuseArgs a2,
                                    float* __restrict__ ws) {
    FuseArgs a = (blockIdx.x == 0) ? a0 : (blockIdx.x == 1 ? a1 : a2);
    const int E = a.E, R = a.R;
    const int tid = threadIdx.x;

    __shared__ float T1[15 * 42];
    __shared__ float b1[15];

    for (int idx = tid; idx < E * TOTAL; idx += blockDim.x) {
        int i = idx / TOTAL, j = idx % TOTAL;
        float acc = 0.f;
        for (int k = 0; k < E; ++k)
            acc = fmaf(a.in_w[(2 * E + i) * E + k], a.kv_w[k * TOTAL + j], acc);
        T1[i * TOTAL + j] = acc;
    }
    if (tid < E) {
        float acc = a.in_b[2 * E + tid];
        for (int k = 0; k < E; ++k)
            acc = fmaf(a.in_w[(2 * E + tid) * E + k], a.kv_b[k], acc);
        b1[tid] = acc;
    }
    __syncthreads();

    for (int idx = tid; idx < E * MPITCH; idx += blockDim.x) {
        int i = idx / MPITCH, j = idx % MPITCH;
        float acc = 0.f;
        if (j < TOTAL)
            for (int k = 0; k < E; ++k)
                acc = fmaf(a.out_w[i * E + k], T1[k * TOTAL + j], acc);
        ws[WS_M + (R + i) * MPITCH + j] = acc;
    }
    if (tid < E) {
        float acc = a.out_b[tid];
        for (int k = 0; k < E; ++k)
            acc = fmaf(a.out_w[tid * E + k], b1[k], acc);
        ws[WS_B + R + tid]    = acc;
        ws[WS_G + R + tid]    = a.ln_g[tid];
        ws[WS_BETA + R + tid] = a.ln_b[tid];
    }
}

// Async global->LDS staging of one segment for one wave. LDS dest is the
// wave-uniform base (HW adds lane*16); global src is per-lane.
template <int CH>
__device__ __forceinline__ void stage_wave(const float* __restrict__ g,
                                           float* lds_seg_base, int lane) {
#pragma unroll
    for (int it = 0; it < (CH + 63) / 64; ++it) {
        int idx = lane + it * 64;
        if (idx < CH) {
            const __attribute__((address_space(1))) void* src =
                (const __attribute__((address_space(1))) void*)
                    ((const char*)g + (size_t)idx * 16);
            __attribute__((address_space(3))) void* dst =
                (__attribute__((address_space(3))) void*)
                    ((char*)lds_seg_base + it * 1024);
            __builtin_amdgcn_global_load_lds(src, dst, 16, 0, 0);
        }
    }
}

// Matvec (packed f32 FMA, scalar-loaded fused weights) + residual + LN.
// Results written into this wave's LDS slice for coalesced store.
template <int E, int R, int SF>
__device__ __forceinline__ void compute_seg(const f2v (&ctx2)[MPITCH / 2],
                                            const float* __restrict__ ws,
                                            float* __restrict__ wb, int lane) {
    const float* ctxs = (const float*)ctx2;
    float y[E];
#pragma unroll
    for (int i = 0; i < E; ++i) {
        CF2* wrow = cast2(ws + WS_M + (R + i) * MPITCH);
        f2v acc = { *cast1(ws + WS_B + R + i), 0.f };
#pragma unroll
        for (int q = 0; q < MPITCH / 2; ++q) {
            f2v w = wrow[q];                  // scalar s_load (K$)
            acc = __builtin_elementwise_fma(w, ctx2[q], acc);  // v_pk_fma_f32
        }
        y[i] = ctxs[R + i] + acc.x + acc.y;   // residual
    }
    float mu = 0.f;
#pragma unroll
    for (int i = 0; i < E; ++i) mu += y[i];
    mu *= (1.0f / E);
    float var = 0.f;
#pragma unroll
    for (int i = 0; i < E; ++i) { float d = y[i] - mu; var = fmaf(d, d, var); }
    var *= (1.0f / E);
    float rs = rsqrtf(var + LN_EPS);
#pragma unroll
    for (int i = 0; i < E; ++i) {
        float n = (y[i] - mu) * rs;
        wb[SF + lane * E + i] = fmaf(n, *cast1(ws + WS_G + R + i),
                                     *cast1(ws + WS_BETA + R + i));
    }
}

__global__ __launch_bounds__(128) void cmca_main(
        const float* __restrict__ cxr, const float* __restrict__ ecg,
        const float* __restrict__ ehr, const float* __restrict__ ws,
        float* __restrict__ out_cxr, float* __restrict__ out_ecg,
        float* __restrict__ out_ehr) {
    __shared__ __align__(16) float sbuf[2 * WFLOATS];   // 21504 B
    const int tid = threadIdx.x;
    const int w = tid >> 6;
    const int lane = tid & 63;
    const size_t gw = (size_t)blockIdx.x * 2 + w;       // global wave-tile id

    float* wb = sbuf + w * WFLOATS;                     // this wave's slice

    const float* g0 = cxr + gw * (size_t)(WROWS * CXR);
    const float* g1 = ecg + gw * (size_t)(WROWS * ECG);
    const float* g2 = ehr + gw * (size_t)(WROWS * EHR);

    // ---- wave-local staging, single latency exposure, NO barriers ----
    stage_wave<WC0>(g0, wb + WS0F, lane);
    stage_wave<WC1>(g1, wb + WS1F, lane);
    stage_wave<WC2>(g2, wb + WS2F, lane);
    asm volatile("s_waitcnt vmcnt(0)" ::: "memory");

    // ---- gather this lane's row into packed registers ----
    f2v ctx2[MPITCH / 2];
    float* ctxs = (float*)ctx2;
#pragma unroll
    for (int j = 0; j < CXR; ++j) ctxs[j] = wb[WS0F + lane * CXR + j];
#pragma unroll
    for (int j = 0; j < ECG; ++j) ctxs[CXR + j] = wb[WS1F + lane * ECG + j];
#pragma unroll
    for (int j = 0; j < EHR; ++j) ctxs[CXR + ECG + j] = wb[WS2F + lane * EHR + j];
    ctxs[42] = 0.f;
    ctxs[43] = 0.f;

    // ---- compute all three segments back into the same LDS slice ----
    // (wave-local LDS ordering: compiler serializes aliasing ds ops via lgkmcnt)
    compute_seg<CXR, 0, WS0F>(ctx2, ws, wb, lane);
    compute_seg<ECG, CXR, WS1F>(ctx2, ws, wb, lane);
    compute_seg<EHR, CXR + ECG, WS2F>(ctx2, ws, wb, lane);

    // ---- coalesced float4 stores from this wave's slice ----
    const float4* wb4 = (const float4*)wb;
    float4* o0 = (float4*)(out_cxr + gw * (size_t)(WROWS * CXR));
    float4* o1 = (float4*)(out_ecg + gw * (size_t)(WROWS * ECG));
    float4* o2 = (float4*)(out_ehr + gw * (size_t)(WROWS * EHR));
#pragma unroll
    for (int it = 0; it < 4; ++it) {
        int idx = lane + it * 64;
        if (idx < WC0) o0[idx] = wb4[idx];
    }
#pragma unroll
    for (int it = 0; it < 4; ++it) {
        int idx = lane + it * 64;
        if (idx < WC1) o1[idx] = wb4[WC0 + idx];
    }
#pragma unroll
    for (int it = 0; it < 4; ++it) {
        int idx = lane + it * 64;
        if (idx < WC2) o2[idx] = wb4[WC0 + WC1 + idx];
    }
}

extern "C" void kernel_launch(void* const* d_in, const int* in_sizes, int n_in,
                              void* d_out, int out_size, void* d_ws, size_t ws_size,
                              hipStream_t stream) {
    const float* cxr = (const float*)d_in[0];
    const float* ecg = (const float*)d_in[1];
    const float* ehr = (const float*)d_in[2];
    float* ws = (float*)d_ws;
    float* out = (float*)d_out;

    const size_t Bn = (size_t)in_sizes[0] / CXR;   // 2097152

    auto mk = [&](int base, int E, int R) {
        FuseArgs a;
        a.in_w  = (const float*)d_in[base + 0];
        a.in_b  = (const float*)d_in[base + 1];
        a.out_w = (const float*)d_in[base + 2];
        a.out_b = (const float*)d_in[base + 3];
        a.kv_w  = (const float*)d_in[base + 4];
        a.kv_b  = (const float*)d_in[base + 5];
        a.ln_g  = (const float*)d_in[base + 6];
        a.ln_b  = (const float*)d_in[base + 7];
        a.E = E; a.R = R;
        return a;
    };
    FuseArgs a0 = mk(3, CXR, 0);
    FuseArgs a1 = mk(11, ECG, CXR);
    FuseArgs a2 = mk(19, EHR, CXR + ECG);

    fuse_weights_kernel<<<3, 256, 0, stream>>>(a0, a1, a2, ws);

    const int nblocks = (int)(Bn / (WROWS * 2));   // 16384 blocks x 2 waves
    cmca_main<<<nblocks, 128, 0, stream>>>(cxr, ecg, ehr, ws,
                                           out,
                                           out + Bn * CXR,
                                           out + Bn * (CXR + ECG));
}

// Round 7
// 146.460 us; speedup vs baseline: 2.9335x; 1.1761x over previous
//
#include <hip/hip_runtime.h>
#include <stdint.h>

// Problem constants
constexpr int CXR = 15, ECG = 14, EHR = 13;
constexpr int TOTAL = 42;
constexpr int MPITCH = 44;         // f32 fused-matrix row pitch (fuse1 output)
constexpr float LN_EPS = 1e-5f;

// Workspace layout (float offsets)
constexpr int WS_M    = 0;                   // A_eff f32, 42 rows x 44 pitch
constexpr int WS_B    = TOTAL * MPITCH;      // fused bias (42)
constexpr int WS_G    = WS_B + TOTAL;        // ln gamma (42)
constexpr int WS_BETA = WS_G + TOTAL;        // ln beta  (42)
constexpr int WS_FRAG = 1976;                // fp16 B-fragments (16B aligned)

// Tiling: 64 rows per wave, 2 waves per block, wave-autonomous (no barriers)
constexpr int WROWS = 64;
constexpr int ARENA_B = 11264;               // per-wave LDS arena (bytes)
// arena phase A: staged f32 concat [2688]; phase B: fp16 X tile [64][64];
// phase C: y f32 [64][44]; phase D: compact f32 results [2688]
constexpr int S0F = 0, S1F = WROWS * CXR, S2F = S1F + WROWS * ECG;  // 0,960,1856
constexpr int WC0 = WROWS * CXR / 4, WC1 = WROWS * ECG / 4, WC2 = WROWS * EHR / 4;

typedef _Float16 half8 __attribute__((ext_vector_type(8)));
typedef float float4v __attribute__((ext_vector_type(4)));
typedef __attribute__((address_space(4))) const float CFc;
__device__ __forceinline__ CFc* cast1(const float* p) {
    return (CFc*)(unsigned long long)p;
}

struct FuseArgs {
    const float *in_w, *in_b, *out_w, *out_b, *kv_w, *kv_b, *ln_g, *ln_b;
    int E, R;
};

// fuse1: A_eff = out_w @ Wv @ kv_w (E x 42), b_eff, ln params -> ws (f32)
__global__ void fuse_weights_kernel(FuseArgs a0, FuseArgs a1, FuseArgs a2,
                                    float* __restrict__ ws) {
    FuseArgs a = (blockIdx.x == 0) ? a0 : (blockIdx.x == 1 ? a1 : a2);
    const int E = a.E, R = a.R;
    const int tid = threadIdx.x;

    __shared__ float T1[15 * 42];
    __shared__ float b1[15];

    for (int idx = tid; idx < E * TOTAL; idx += blockDim.x) {
        int i = idx / TOTAL, j = idx % TOTAL;
        float acc = 0.f;
        for (int k = 0; k < E; ++k)
            acc = fmaf(a.in_w[(2 * E + i) * E + k], a.kv_w[k * TOTAL + j], acc);
        T1[i * TOTAL + j] = acc;
    }
    if (tid < E) {
        float acc = a.in_b[2 * E + tid];
        for (int k = 0; k < E; ++k)
            acc = fmaf(a.in_w[(2 * E + tid) * E + k], a.kv_b[k], acc);
        b1[tid] = acc;
    }
    __syncthreads();

    for (int idx = tid; idx < E * MPITCH; idx += blockDim.x) {
        int i = idx / MPITCH, j = idx % MPITCH;
        float acc = 0.f;
        if (j < TOTAL)
            for (int k = 0; k < E; ++k)
                acc = fmaf(a.out_w[i * E + k], T1[k * TOTAL + j], acc);
        ws[WS_M + (R + i) * MPITCH + j] = acc;
    }
    if (tid < E) {
        float acc = a.out_b[tid];
        for (int k = 0; k < E; ++k)
            acc = fmaf(a.out_w[tid * E + k], b1[k], acc);
        ws[WS_B + R + tid]    = acc;
        ws[WS_G + R + tid]    = a.ln_g[tid];
        ws[WS_BETA + R + tid] = a.ln_b[tid];
    }
}

// fuse2: build fp16 B-fragments in MFMA lane order. W[k][col] = A_eff[col][k]
// + identity (k==col) + bias row (k==42). k-packing: elem i <-> k0+i,
// k0 = t*32 + 8*(lane>>4) (same bijection used for A-frags in main kernel).
__global__ void fuse_frags_kernel(float* __restrict__ ws) {
    const int tid = threadIdx.x;          // 0..383
    if (tid >= 384) return;
    const int l = tid & 63, nt = tid >> 6;
    const int n = nt >> 1, t = nt & 1;
    const int col = n * 16 + (l & 15);
    const int k0 = t * 32 + 8 * (l >> 4);
    half8 h;
#pragma unroll
    for (int i = 0; i < 8; ++i) {
        int k = k0 + i;
        float v = 0.f;
        if (col < TOTAL) {
            if (k < TOTAL) {
                v = ws[WS_M + col * MPITCH + k];
                if (k == col) v += 1.f;               // residual identity
            } else if (k == TOTAL) {
                v = ws[WS_B + col];                   // bias via 1.0 column
            }
        }
        h[i] = (_Float16)v;
    }
    ((half8*)(ws + WS_FRAG))[nt * 64 + l] = h;
}

// Async global->LDS staging (linear, width 16).
template <int CH>
__device__ __forceinline__ void stage_wave(const float* __restrict__ g,
                                           float* lds_seg_base, int lane) {
#pragma unroll
    for (int it = 0; it < (CH + 63) / 64; ++it) {
        int idx = lane + it * 64;
        if (idx < CH) {
            const __attribute__((address_space(1))) void* src =
                (const __attribute__((address_space(1))) void*)
                    ((const char*)g + (size_t)idx * 16);
            __attribute__((address_space(3))) void* dst =
                (__attribute__((address_space(3))) void*)
                    ((char*)lds_seg_base + it * 1024);
            __builtin_amdgcn_global_load_lds(src, dst, 16, 0, 0);
        }
    }
}

__global__ __launch_bounds__(128) void cmca_main(
        const float* __restrict__ cxr, const float* __restrict__ ecg,
        const float* __restrict__ ehr, const float* __restrict__ ws,
        float* __restrict__ out_cxr, float* __restrict__ out_ecg,
        float* __restrict__ out_ehr) {
    __shared__ __align__(16) char smem[2 * ARENA_B];
    const int tid = threadIdx.x;
    const int w = tid >> 6, lane = tid & 63;
    char* arena = smem + w * ARENA_B;
    float* af = (float*)arena;
    const size_t gw = (size_t)blockIdx.x * 2 + w;

    // ---- B-fragments (6 x 16B coalesced, L2-hot) ----
    const half8* fr = (const half8*)(ws + WS_FRAG);
    half8 bfrag[6];
#pragma unroll
    for (int q = 0; q < 6; ++q) bfrag[q] = fr[q * 64 + lane];

    // ---- stage all three segments into arena (linear f32) ----
    stage_wave<WC0>(cxr + gw * (size_t)(WROWS * CXR), af + S0F, lane);
    stage_wave<WC1>(ecg + gw * (size_t)(WROWS * ECG), af + S1F, lane);
    stage_wave<WC2>(ehr + gw * (size_t)(WROWS * EHR), af + S2F, lane);
    asm volatile("s_waitcnt vmcnt(0)" ::: "memory");

    // ---- gather this lane's row (f32) ----
    float x[TOTAL];
#pragma unroll
    for (int j = 0; j < CXR; ++j) x[j] = af[S0F + lane * CXR + j];
#pragma unroll
    for (int j = 0; j < ECG; ++j) x[CXR + j] = af[S1F + lane * ECG + j];
#pragma unroll
    for (int j = 0; j < EHR; ++j) x[CXR + ECG + j] = af[S2F + lane * EHR + j];
    __builtin_amdgcn_sched_barrier(0);

    // ---- write fp16 X row [64 halfs], swizzled; x[42]=1.0, pad=0 ----
    {
        const int swz = (lane & 7) << 4;
#pragma unroll
        for (int j = 0; j < 8; ++j) {
            half8 h;
#pragma unroll
            for (int e = 0; e < 8; ++e) {
                int idx = j * 8 + e;
                float v = (idx < TOTAL) ? x[idx] : (idx == TOTAL ? 1.f : 0.f);
                h[e] = (_Float16)v;
            }
            *(half8*)(arena + ((lane * 128 + j * 16) ^ swz)) = h;
        }
    }
    __builtin_amdgcn_sched_barrier(0);

    // ---- read A-fragments (one b128 per m,t) ----
    half8 afr[4][2];
#pragma unroll
    for (int m = 0; m < 4; ++m) {
        int row = m * 16 + (lane & 15);
        int rswz = (row & 7) << 4;
#pragma unroll
        for (int t = 0; t < 2; ++t)
            afr[m][t] = *(const half8*)(arena +
                ((row * 128 + t * 64 + (lane >> 4) * 16) ^ rswz));
    }
    __builtin_amdgcn_sched_barrier(0);

    // ---- 24 MFMAs: Y[64x48] = X[64x64] * W[64x48] ----
    float4v acc[4][3];
#pragma unroll
    for (int m = 0; m < 4; ++m)
#pragma unroll
        for (int n = 0; n < 3; ++n) acc[m][n] = float4v{0.f, 0.f, 0.f, 0.f};
#pragma unroll
    for (int t = 0; t < 2; ++t)
#pragma unroll
        for (int m = 0; m < 4; ++m)
#pragma unroll
            for (int n = 0; n < 3; ++n)
                acc[m][n] = __builtin_amdgcn_mfma_f32_16x16x32_f16(
                    afr[m][t], bfrag[n * 2 + t], acc[m][n], 0, 0, 0);

    // ---- scatter y to [row][44] f32 tile ----
    __builtin_amdgcn_sched_barrier(0);
#pragma unroll
    for (int m = 0; m < 4; ++m)
#pragma unroll
        for (int n = 0; n < 3; ++n)
#pragma unroll
            for (int r = 0; r < 4; ++r) {
                int row = m * 16 + (lane >> 4) * 4 + r;
                int col = n * 16 + (lane & 15);
                if (col < MPITCH) af[row * MPITCH + col] = acc[m][n][r];
            }
    __builtin_amdgcn_sched_barrier(0);

    // ---- epilogue (lane = row): gather y, per-segment LN, compact write ----
    float y[MPITCH];
#pragma unroll
    for (int j = 0; j < 11; ++j) {
        float4v q = *(const float4v*)(af + lane * MPITCH + j * 4);
        y[j * 4 + 0] = q[0]; y[j * 4 + 1] = q[1];
        y[j * 4 + 2] = q[2]; y[j * 4 + 3] = q[3];
    }
    __builtin_amdgcn_sched_barrier(0);

    float res[TOTAL];
    {
        // seg helper, fully unrolled per segment
#define LN_SEG(S, E)                                                       \
        {                                                                  \
            float mu = 0.f;                                                \
            _Pragma("unroll")                                              \
            for (int i = 0; i < (E); ++i) mu += y[(S) + i];                \
            mu *= (1.0f / (E));                                            \
            float var = 0.f;                                               \
            _Pragma("unroll")                                              \
            for (int i = 0; i < (E); ++i) {                                \
                float d = y[(S) + i] - mu; var = fmaf(d, d, var);          \
            }                                                              \
            var *= (1.0f / (E));                                           \
            float rs = rsqrtf(var + LN_EPS);                               \
            _Pragma("unroll")                                              \
            for (int i = 0; i < (E); ++i) {                                \
                float nv = (y[(S) + i] - mu) * rs;                         \
                res[(S) + i] = fmaf(nv, *cast1(ws + WS_G + (S) + i),       \
                                    *cast1(ws + WS_BETA + (S) + i));       \
            }                                                              \
        }
        LN_SEG(0, CXR)
        LN_SEG(CXR, ECG)
        LN_SEG(CXR + ECG, EHR)
#undef LN_SEG
    }
#pragma unroll
    for (int j = 0; j < CXR; ++j) af[S0F + lane * CXR + j] = res[j];
#pragma unroll
    for (int j = 0; j < ECG; ++j) af[S1F + lane * ECG + j] = res[CXR + j];
#pragma unroll
    for (int j = 0; j < EHR; ++j) af[S2F + lane * EHR + j] = res[CXR + ECG + j];
    __builtin_amdgcn_sched_barrier(0);

    // ---- coalesced float4 stores ----
    const float4v* wb4 = (const float4v*)af;
    float4v* o0 = (float4v*)(out_cxr + gw * (size_t)(WROWS * CXR));
    float4v* o1 = (float4v*)(out_ecg + gw * (size_t)(WROWS * ECG));
    float4v* o2 = (float4v*)(out_ehr + gw * (size_t)(WROWS * EHR));
#pragma unroll
    for (int it = 0; it < 4; ++it) {
        int idx = lane + it * 64;
        if (idx < WC0) o0[idx] = wb4[idx];
    }
#pragma unroll
    for (int it = 0; it < 4; ++it) {
        int idx = lane + it * 64;
        if (idx < WC1) o1[idx] = wb4[WC0 + idx];
    }
#pragma unroll
    for (int it = 0; it < 4; ++it) {
        int idx = lane + it * 64;
        if (idx < WC2) o2[idx] = wb4[WC0 + WC1 + idx];
    }
}

extern "C" void kernel_launch(void* const* d_in, const int* in_sizes, int n_in,
                              void* d_out, int out_size, void* d_ws, size_t ws_size,
                              hipStream_t stream) {
    const float* cxr = (const float*)d_in[0];
    const float* ecg = (const float*)d_in[1];
    const float* ehr = (const float*)d_in[2];
    float* ws = (float*)d_ws;
    float* out = (float*)d_out;

    const size_t Bn = (size_t)in_sizes[0] / CXR;   // 2097152

    auto mk = [&](int base, int E, int R) {
        FuseArgs a;
        a.in_w  = (const float*)d_in[base + 0];
        a.in_b  = (const float*)d_in[base + 1];
        a.out_w = (const float*)d_in[base + 2];
        a.out_b = (const float*)d_in[base + 3];
        a.kv_w  = (const float*)d_in[base + 4];
        a.kv_b  = (const float*)d_in[base + 5];
        a.ln_g  = (const float*)d_in[base + 6];
        a.ln_b  = (const float*)d_in[base + 7];
        a.E = E; a.R = R;
        return a;
    };
    FuseArgs a0 = mk(3, CXR, 0);
    FuseArgs a1 = mk(11, ECG, CXR);
    FuseArgs a2 = mk(19, EHR, CXR + ECG);

    fuse_weights_kernel<<<3, 256, 0, stream>>>(a0, a1, a2, ws);
    fuse_frags_kernel<<<1, 384, 0, stream>>>(ws);

    const int nblocks = (int)(Bn / (WROWS * 2));   // 16384
    cmca_main<<<nblocks, 128, 0, stream>>>(cxr, ecg, ehr, ws,
                                           out,
                                           out + Bn * CXR,
                                           out + Bn * (CXR + ECG));
}